// Round 9
// baseline (1087.690 us; speedup 1.0000x reference)
//
#include <hip/hip_runtime.h>

#define B_TOT 262144
#define HID   256
#define NHEAD 8
#define BR    64        // rows per tile
#define NTILE 8         // tiles per block (persistent)
#define NBLK  512       // 2 blocks per CU
#define NTHR  256       // 4 waves; wave owns 16 batch rows end-to-end

typedef __bf16 bf16_t;
typedef __attribute__((ext_vector_type(8))) __bf16 bf16x8;
typedef __attribute__((ext_vector_type(4))) __bf16 bf16x4;
typedef __attribute__((ext_vector_type(4))) float  f32x4;

// d_ws layout (bf16, fragment-ordered; byte = chunk*1024 + lane*16):
//   QKV: chunk = (h*8+ks)*6 + wi*2 + half   (wi: 0=q 1=k 2=v), chunk in [0,384)
//        element = W[h*32 + PI(lane&15,half)][ks*32 + (lane>>4)*8 .. +8]
//        PI(m,half) = (m>>2)*8 + half*4 + (m&3)
//        (PI makes attention-mix C-frags == out-proj B-frags, no shuffles)
//   Wo:  chunk = 384 + ks*16 + jt, chunk in [384,512)
//        element = Wo[jt*16 + (lane&15)][ks*32 + (lane>>4)*8 .. +8]
#define QKV_BYTES (384 * 1024)

static __device__ __forceinline__ f32x4 mfma16(bf16x8 a, bf16x8 b, f32x4 c) {
  return __builtin_amdgcn_mfma_f32_16x16x32_bf16(a, b, c, 0, 0, 0);
}

static __device__ __forceinline__ bf16x8 cvt8(float4 a, float4 b) {
  bf16x8 r;
  r[0] = (bf16_t)a.x; r[1] = (bf16_t)a.y; r[2] = (bf16_t)a.z; r[3] = (bf16_t)a.w;
  r[4] = (bf16_t)b.x; r[5] = (bf16_t)b.y; r[6] = (bf16_t)b.z; r[7] = (bf16_t)b.w;
  return r;
}

// opaque register pin: forbids rematerialization of the producing loads
static __device__ __forceinline__ bf16x8 pin8(bf16x8 v) {
  f32x4 t = __builtin_bit_cast(f32x4, v);
  asm volatile("" : "+v"(t));
  return __builtin_bit_cast(bf16x8, t);
}

typedef __attribute__((address_space(3))) void lds_void;
typedef __attribute__((address_space(1))) void gbl_void;
static __device__ __forceinline__ void gload_lds16(const void* g, void* l) {
  __builtin_amdgcn_global_load_lds((gbl_void*)g, (lds_void*)l, 16, 0, 0);
}

// ---- one-shot weight pack: f32 row-major -> bf16 fragment-ordered in ws ----
__global__ __launch_bounds__(256) void pack_weights(
    const float* __restrict__ Wq, const float* __restrict__ Wk,
    const float* __restrict__ Wv, const float* __restrict__ Wo,
    bf16_t* __restrict__ ws) {
  const int t     = blockIdx.x * 256 + threadIdx.x;   // 0..32767
  const int lane  = t & 63;
  const int chunk = t >> 6;                           // 0..511
  const int l15 = lane & 15, lg = lane >> 4;
  const float* src;
  int row, col;
  if (chunk < 384) {
    const int slot = chunk % 6;
    const int hk   = chunk / 6;
    const int wi = slot >> 1, half = slot & 1;
    const int h = hk >> 3, ks = hk & 7;
    src = (wi == 0) ? Wq : (wi == 1) ? Wk : Wv;
    row = h * 32 + (l15 >> 2) * 8 + half * 4 + (l15 & 3);   // PI permutation
    col = ks * 32 + lg * 8;
  } else {
    const int c  = chunk - 384;
    const int ks = c >> 4, jt = c & 15;
    src = Wo;
    row = jt * 16 + l15;
    col = ks * 32 + lg * 8;
  }
  const float* p = src + (size_t)row * HID + col;
  const float4 a = *(const float4*)p;
  const float4 b = *(const float4*)(p + 4);
  *(bf16x8*)(ws + (size_t)t * 8) = cvt8(a, b);
}

__global__ __launch_bounds__(NTHR, 2) void fused_local_aug(
    const float* __restrict__ fine, const float* __restrict__ coarse,
    const float* __restrict__ motif, const bf16_t* __restrict__ wpk,
    const float* __restrict__ bo, float* __restrict__ out) {
  // double-buffered W staging: 2 x 24 KB = 48 KB -> 2 blocks/CU co-resident
  __shared__ char wbuf[49152];

  const int tid  = threadIdx.x;
  const int lane = tid & 63;
  const int wave = tid >> 6;
  const int l15  = lane & 15;
  const int lg   = lane >> 4;
  const size_t brow0 = (size_t)blockIdx.x * (BR * NTILE);
  const int    wlofs = wave * 16 + l15;   // row offset within a tile

  // phase table per tile: ph 0..15 = (head h=ph>>1, half=ph&1), 24 KB each
  //                       ph 16..23 = Wo ks-slot (ph-16), 16 KB each
  // parity = ph&1; 24 phases/tile (even) -> parity pattern repeats every tile.
  auto stage = [&](int ph) {       // ph already wrapped to [0,24)
    char* dst = wbuf + (ph & 1) * 24576 + tid * 16;
    if (ph < 16) {
      const char* src = (const char*)wpk + (ph >> 1) * 49152 + (ph & 1) * 24576 + tid * 16;
#pragma unroll
      for (int i = 0; i < 6; ++i)
        gload_lds16(src + i * 4096, dst + i * 4096);
    } else {
      const char* src = (const char*)wpk + QKV_BYTES + (ph - 16) * 16384 + tid * 16;
#pragma unroll
      for (int i = 0; i < 4; ++i)
        gload_lds16(src + i * 4096, dst + i * 4096);
    }
  };

  stage(0);   // prefetch first W phase under the tile-0 X prologue

  // ---- X registers for the CURRENT tile (refilled during Wo phases) ----
  bf16x8 xm[8], xf[8], xc[8];
  {
    const size_t mrow = brow0 + wlofs;            // tile 0 rows
    const float* pm = motif  + mrow * HID + lg * 8;
    const float* pf = fine   + mrow * HID + lg * 8;
    const float* pc = coarse + mrow * HID + lg * 8;
#pragma unroll
    for (int s = 0; s < 8; ++s) {
      xm[s] = pin8(cvt8(*(const float4*)(pm + s * 32), *(const float4*)(pm + s * 32 + 4)));
      xf[s] = pin8(cvt8(*(const float4*)(pf + s * 32), *(const float4*)(pf + s * 32 + 4)));
      xc[s] = pin8(cvt8(*(const float4*)(pc + s * 32), *(const float4*)(pc + s * 32 + 4)));
    }
  }
  __syncthreads();   // phase 0 staged for all waves

#pragma unroll 1
  for (int tile = 0; tile < NTILE; ++tile) {
    const size_t mrow = brow0 + tile * BR + wlofs;     // this lane's batch row

    // mid in registers: mo0[h][r] = feature h*32+lg*8+r, mo1[h][r] = +4
    bf16x4 mo0[NHEAD], mo1[NHEAD];

    // ---- head loop: 16 pipelined phases, one barrier each ----
#pragma unroll
    for (int h = 0; h < NHEAD; ++h) {
      f32x4 aQ0{}, aQ1{}, aK10{}, aK11{}, aK20{}, aK21{}, aV10{}, aV11{}, aV20{}, aV21{};
#pragma unroll
      for (int half = 0; half < 2; ++half) {
        stage(2 * h + half + 1);               // issue next phase's W loads FIRST
        const char* pb = wbuf + ((2 * h + half) & 1) * 24576 + lane * 16;
#pragma unroll
        for (int kk = 0; kk < 4; ++kk) {
          const int ks = half * 4 + kk;
          const char* p = pb + kk * 6144;
          bf16x8 q0 = *(const bf16x8*)(p);
          bf16x8 q1 = *(const bf16x8*)(p + 1024);
          bf16x8 k0 = *(const bf16x8*)(p + 2048);
          bf16x8 k1 = *(const bf16x8*)(p + 3072);
          bf16x8 v0 = *(const bf16x8*)(p + 4096);
          bf16x8 v1 = *(const bf16x8*)(p + 5120);
          aQ0  = mfma16(q0, xm[ks], aQ0);   aQ1  = mfma16(q1, xm[ks], aQ1);
          aK10 = mfma16(k0, xf[ks], aK10);  aK11 = mfma16(k1, xf[ks], aK11);
          aK20 = mfma16(k0, xc[ks], aK20);  aK21 = mfma16(k1, xc[ks], aK21);
          aV10 = mfma16(v0, xf[ks], aV10);  aV11 = mfma16(v1, xf[ks], aV11);
          aV20 = mfma16(v0, xc[ks], aV20);  aV21 = mfma16(v1, xc[ks], aV21);
        }
        __syncthreads();
      }
      float s1 = 0.f, s2 = 0.f;
#pragma unroll
      for (int r = 0; r < 4; ++r) {
        s1 += aQ0[r] * aK10[r] + aQ1[r] * aK11[r];
        s2 += aQ0[r] * aK20[r] + aQ1[r] * aK21[r];
      }
      s1 += __shfl_xor(s1, 16); s1 += __shfl_xor(s1, 32);
      s2 += __shfl_xor(s2, 16); s2 += __shfl_xor(s2, 32);
      s1 *= (1.0f / 32.0f);  s2 *= (1.0f / 32.0f);   // reference divides by d_k
      const float mx = fmaxf(s1, s2);
      const float e1 = __expf(s1 - mx), e2 = __expf(s2 - mx);
      const float a1 = e1 / (e1 + e2);
      const float a2 = 1.0f - a1;
#pragma unroll
      for (int r = 0; r < 4; ++r) {
        mo0[h][r] = (bf16_t)(a1 * aV10[r] + a2 * aV20[r]);
        mo1[h][r] = (bf16_t)(a1 * aV11[r] + a2 * aV21[r]);
      }
    }

    // ---- out-proj B-frags (PI pack makes this a pure concat) ----
    bf16x8 mfrag[NHEAD];
#pragma unroll
    for (int h = 0; h < NHEAD; ++h) {
      bf16x8 t;
      t[0] = mo0[h][0]; t[1] = mo0[h][1]; t[2] = mo0[h][2]; t[3] = mo0[h][3];
      t[4] = mo1[h][0]; t[5] = mo1[h][1]; t[6] = mo1[h][2]; t[7] = mo1[h][3];
      mfrag[h] = t;
    }

    // ---- output projection: 8 Wo phases; X[tile+1] refills xm/xf/xc here ----
    f32x4 acc[16];
#pragma unroll
    for (int jt = 0; jt < 16; ++jt) acc[jt] = f32x4{0.f, 0.f, 0.f, 0.f};

    const bool more = (tile + 1 < NTILE);
    const size_t nrow = mrow + BR;                 // next tile's row (same lane)
    const float* npm = motif  + nrow * HID + lg * 8;
    const float* npf = fine   + nrow * HID + lg * 8;
    const float* npc = coarse + nrow * HID + lg * 8;

#pragma unroll
    for (int wp = 0; wp < 8; ++wp) {               // phase 16+wp
      // issue next-tile X loads for segment wp (consumed at end of this phase)
      float4 nm0, nm1, nf0, nf1, nc0, nc1;
      if (more) {
        nm0 = *(const float4*)(npm + wp * 32); nm1 = *(const float4*)(npm + wp * 32 + 4);
        nf0 = *(const float4*)(npf + wp * 32); nf1 = *(const float4*)(npf + wp * 32 + 4);
        nc0 = *(const float4*)(npc + wp * 32); nc1 = *(const float4*)(npc + wp * 32 + 4);
      }
      stage((17 + wp) % 24);                       // wp=7 stages next tile's phase 0
      bf16x8 mf = mfrag[wp];
      const char* pb = wbuf + (wp & 1) * 24576 + lane * 16;
#pragma unroll
      for (int jt = 0; jt < 16; ++jt) {
        bf16x8 wf = *(const bf16x8*)(pb + jt * 1024);
        acc[jt] = mfma16(wf, mf, acc[jt]);
      }
      if (more) {                                  // cvt after compute: loads in flight
        xm[wp] = pin8(cvt8(nm0, nm1));
        xf[wp] = pin8(cvt8(nf0, nf1));
        xc[wp] = pin8(cvt8(nc0, nc1));
      }
      __syncthreads();
    }

    // epilogue: bias + NT stores; lane writes 16B chunks of its own full row
#pragma unroll
    for (int jt = 0; jt < 16; ++jt) {
      const int jj = jt * 16 + lg * 4;
      const float4 b4 = *(const float4*)(bo + jj);
      f32x4 o;
      o[0] = acc[jt][0] + b4.x;
      o[1] = acc[jt][1] + b4.y;
      o[2] = acc[jt][2] + b4.z;
      o[3] = acc[jt][3] + b4.w;
      __builtin_nontemporal_store(o, (f32x4*)(out + mrow * HID + jj));
    }
  }
}

extern "C" void kernel_launch(void* const* d_in, const int* in_sizes, int n_in,
                              void* d_out, int out_size, void* d_ws, size_t ws_size,
                              hipStream_t stream) {
  (void)in_sizes; (void)n_in; (void)ws_size; (void)out_size;
  const float* fine   = (const float*)d_in[0];
  const float* coarse = (const float*)d_in[1];
  const float* motif  = (const float*)d_in[2];
  const float* Wq     = (const float*)d_in[3];
  const float* Wk     = (const float*)d_in[4];
  const float* Wv     = (const float*)d_in[5];
  const float* Wo     = (const float*)d_in[6];
  const float* bo     = (const float*)d_in[7];
  float* out          = (float*)d_out;
  bf16_t* wpk         = (bf16_t*)d_ws;

  pack_weights<<<128, 256, 0, stream>>>(Wq, Wk, Wv, Wo, wpk);
  fused_local_aug<<<NBLK, NTHR, 0, stream>>>(fine, coarse, motif, wpk, bo, out);
}

// Round 11
// 357.058 us; speedup vs baseline: 3.0463x; 3.0463x over previous
//
#include <hip/hip_runtime.h>

#define B_TOT 262144
#define HID   256
#define NHEAD 8
#define BR    64       // rows per block
#define NTHR  256      // 4 waves; wave owns 16 batch rows end-to-end

typedef __bf16 bf16_t;
typedef __attribute__((ext_vector_type(8))) __bf16 bf16x8;
typedef __attribute__((ext_vector_type(4))) __bf16 bf16x4;
typedef __attribute__((ext_vector_type(4))) float  f32x4;

// d_ws layout (bf16, fragment-ordered; byte = chunk*1024 + lane*16):
//   QKV: chunk = (h*8+ks)*6 + wi*2 + half   (wi: 0=q 1=k 2=v), chunk in [0,384)
//        element = W[h*32 + PI(lane&15,half)][ks*32 + (lane>>4)*8 .. +8]
//        PI(m,half) = (m>>2)*8 + half*4 + (m&3)
//        (PI makes attention-mix C-frags == out-proj B-frags, no shuffles)
//   Wo:  chunk = 384 + ks*16 + jt, chunk in [384,512)
//        element = Wo[jt*16 + (lane&15)][ks*32 + (lane>>4)*8 .. +8]
#define QKV_BYTES (384 * 1024)

// phase table: p 0..15 = QKV (head p>>1, half p&1), 24 KB; p 16..23 = Wo slot, 16 KB.
// 3 LDS buffers of 24 KB; phase p uses buffer p%3. stage(p+2) issued inside phase p.
// At the barrier entering phase p, only stage(p+1) may remain outstanding:
//   wait vmcnt(L[p+1]) where L = 6 (QKV) / 4 (Wo) / 0 (none).
// lgkmcnt(0) is REQUIRED (race fix, R9 post-mortem): it guarantees every wave's
// ds_reads of the retiring buffer completed before the barrier, so stage(p+2)'s
// DMA writes (issued post-barrier into that buffer) cannot clobber pending reads.
#define PHASE_SYNC(N)                                                  \
  do {                                                                 \
    asm volatile("s_waitcnt vmcnt(" #N ") lgkmcnt(0)" ::: "memory");   \
    __builtin_amdgcn_s_barrier();                                      \
    __builtin_amdgcn_sched_barrier(0);                                 \
  } while (0)

static __device__ __forceinline__ f32x4 mfma16(bf16x8 a, bf16x8 b, f32x4 c) {
  return __builtin_amdgcn_mfma_f32_16x16x32_bf16(a, b, c, 0, 0, 0);
}

static __device__ __forceinline__ bf16x8 cvt8(float4 a, float4 b) {
  bf16x8 r;
  r[0] = (bf16_t)a.x; r[1] = (bf16_t)a.y; r[2] = (bf16_t)a.z; r[3] = (bf16_t)a.w;
  r[4] = (bf16_t)b.x; r[5] = (bf16_t)b.y; r[6] = (bf16_t)b.z; r[7] = (bf16_t)b.w;
  return r;
}

// opaque register pin: forbids rematerialization of the producing loads
static __device__ __forceinline__ bf16x8 pin8(bf16x8 v) {
  f32x4 t = __builtin_bit_cast(f32x4, v);
  asm volatile("" : "+v"(t));
  return __builtin_bit_cast(bf16x8, t);
}

typedef __attribute__((address_space(3))) void lds_void;
typedef __attribute__((address_space(1))) void gbl_void;
static __device__ __forceinline__ void gload_lds16(const void* g, void* l) {
  __builtin_amdgcn_global_load_lds((gbl_void*)g, (lds_void*)l, 16, 0, 0);
}

// ---- one-shot weight pack: f32 row-major -> bf16 fragment-ordered in ws ----
__global__ __launch_bounds__(256) void pack_weights(
    const float* __restrict__ Wq, const float* __restrict__ Wk,
    const float* __restrict__ Wv, const float* __restrict__ Wo,
    bf16_t* __restrict__ ws) {
  const int t     = blockIdx.x * 256 + threadIdx.x;   // 0..32767
  const int lane  = t & 63;
  const int chunk = t >> 6;                           // 0..511
  const int l15 = lane & 15, lg = lane >> 4;
  const float* src;
  int row, col;
  if (chunk < 384) {
    const int slot = chunk % 6;
    const int hk   = chunk / 6;
    const int wi = slot >> 1, half = slot & 1;
    const int h = hk >> 3, ks = hk & 7;
    src = (wi == 0) ? Wq : (wi == 1) ? Wk : Wv;
    row = h * 32 + (l15 >> 2) * 8 + half * 4 + (l15 & 3);   // PI permutation
    col = ks * 32 + lg * 8;
  } else {
    const int c  = chunk - 384;
    const int ks = c >> 4, jt = c & 15;
    src = Wo;
    row = jt * 16 + l15;
    col = ks * 32 + lg * 8;
  }
  const float* p = src + (size_t)row * HID + col;
  const float4 a = *(const float4*)p;
  const float4 b = *(const float4*)(p + 4);
  *(bf16x8*)(ws + (size_t)t * 8) = cvt8(a, b);
}

__global__ __launch_bounds__(NTHR, 2) void fused_local_aug(
    const float* __restrict__ fine, const float* __restrict__ coarse,
    const float* __restrict__ motif, const bf16_t* __restrict__ wpk,
    const float* __restrict__ bo, float* __restrict__ out) {
  // triple-buffered W staging: 3 x 24 KB = 72 KB -> 2 blocks/CU co-resident
  __shared__ char wbuf[73728];

  const int tid  = threadIdx.x;
  const int lane = tid & 63;
  const int wave = tid >> 6;
  const int l15  = lane & 15;
  const int lg   = lane >> 4;
  const size_t row0 = (size_t)blockIdx.x * BR;
  const size_t mrow = row0 + wave * 16 + l15;   // this lane's batch row

  auto stage = [&](int ph) {       // issues 6 (QKV) or 4 (Wo) gload_lds per thread
    char* dst = wbuf + (ph % 3) * 24576 + tid * 16;
    if (ph < 16) {
      const char* src = (const char*)wpk + (ph >> 1) * 49152 + (ph & 1) * 24576 + tid * 16;
#pragma unroll
      for (int i = 0; i < 6; ++i)
        gload_lds16(src + i * 4096, dst + i * 4096);
    } else {
      const char* src = (const char*)wpk + QKV_BYTES + (ph - 16) * 16384 + tid * 16;
#pragma unroll
      for (int i = 0; i < 4; ++i)
        gload_lds16(src + i * 4096, dst + i * 4096);
    }
  };

  stage(0);
  stage(1);   // both prefetched under the X prologue

  // ---- preload this wave's 16 X rows into pinned bf16 register fragments ----
  bf16x8 xm[8], xf[8], xc[8];
  {
    const float* pm = motif  + mrow * HID + lg * 8;
    const float* pf = fine   + mrow * HID + lg * 8;
    const float* pc = coarse + mrow * HID + lg * 8;
#pragma unroll
    for (int s = 0; s < 8; ++s) {
      xm[s] = pin8(cvt8(*(const float4*)(pm + s * 32), *(const float4*)(pm + s * 32 + 4)));
      xf[s] = pin8(cvt8(*(const float4*)(pf + s * 32), *(const float4*)(pf + s * 32 + 4)));
      xc[s] = pin8(cvt8(*(const float4*)(pc + s * 32), *(const float4*)(pc + s * 32 + 4)));
    }
  }
  __syncthreads();   // full drain once: phases 0 and 1 staged for all waves

  // mid in registers: mo0[h][r] = feature h*32+lg*8+r, mo1[h][r] = +4
  bf16x4 mo0[NHEAD], mo1[NHEAD];

  // ---- head loop: phases p = 2h+half, one counted-vmcnt barrier per phase ----
#pragma unroll
  for (int h = 0; h < NHEAD; ++h) {
    f32x4 aQ0{}, aQ1{}, aK10{}, aK11{}, aK20{}, aK21{}, aV10{}, aV11{}, aV20{}, aV21{};
#pragma unroll
    for (int half = 0; half < 2; ++half) {
      const int p = 2 * h + half;
      if (p > 0) {
        if (p == 15) { PHASE_SYNC(4); }   // next in flight is Wo slot (4 loads)
        else         { PHASE_SYNC(6); }
      }
      stage(p + 2);                       // p+2 <= 17, safe after barrier (WAR closed)
      const char* pb = wbuf + (p % 3) * 24576 + lane * 16;
#pragma unroll
      for (int kk = 0; kk < 4; ++kk) {
        const int ks = half * 4 + kk;
        const char* q = pb + kk * 6144;
        bf16x8 q0 = *(const bf16x8*)(q);
        bf16x8 q1 = *(const bf16x8*)(q + 1024);
        bf16x8 k0 = *(const bf16x8*)(q + 2048);
        bf16x8 k1 = *(const bf16x8*)(q + 3072);
        bf16x8 v0 = *(const bf16x8*)(q + 4096);
        bf16x8 v1 = *(const bf16x8*)(q + 5120);
        aQ0  = mfma16(q0, xm[ks], aQ0);   aQ1  = mfma16(q1, xm[ks], aQ1);
        aK10 = mfma16(k0, xf[ks], aK10);  aK11 = mfma16(k1, xf[ks], aK11);
        aK20 = mfma16(k0, xc[ks], aK20);  aK21 = mfma16(k1, xc[ks], aK21);
        aV10 = mfma16(v0, xf[ks], aV10);  aV11 = mfma16(v1, xf[ks], aV11);
        aV20 = mfma16(v0, xc[ks], aV20);  aV21 = mfma16(v1, xc[ks], aV21);
      }
    }
    // scores for this lane's batch row: reduce regs + lane>>4 groups
    float s1 = 0.f, s2 = 0.f;
#pragma unroll
    for (int r = 0; r < 4; ++r) {
      s1 += aQ0[r] * aK10[r] + aQ1[r] * aK11[r];
      s2 += aQ0[r] * aK20[r] + aQ1[r] * aK21[r];
    }
    s1 += __shfl_xor(s1, 16); s1 += __shfl_xor(s1, 32);
    s2 += __shfl_xor(s2, 16); s2 += __shfl_xor(s2, 32);
    s1 *= (1.0f / 32.0f);  s2 *= (1.0f / 32.0f);   // reference divides by d_k
    const float mx = fmaxf(s1, s2);
    const float e1 = __expf(s1 - mx), e2 = __expf(s2 - mx);
    const float a1 = e1 / (e1 + e2);
    const float a2 = 1.0f - a1;
#pragma unroll
    for (int r = 0; r < 4; ++r) {
      mo0[h][r] = (bf16_t)(a1 * aV10[r] + a2 * aV20[r]);
      mo1[h][r] = (bf16_t)(a1 * aV11[r] + a2 * aV21[r]);
    }
  }

  // ---- out-proj B-frags (PI pack makes this a pure concat) ----
  bf16x8 mfrag[NHEAD];
#pragma unroll
  for (int h = 0; h < NHEAD; ++h) {
    bf16x8 t;
    t[0] = mo0[h][0]; t[1] = mo0[h][1]; t[2] = mo0[h][2]; t[3] = mo0[h][3];
    t[4] = mo1[h][0]; t[5] = mo1[h][1]; t[6] = mo1[h][2]; t[7] = mo1[h][3];
    mfrag[h] = t;
  }

  // ---- output projection: 8 pipelined Wo phases (p = 16+wp) ----
  f32x4 acc[16];
#pragma unroll
  for (int jt = 0; jt < 16; ++jt) acc[jt] = f32x4{0.f, 0.f, 0.f, 0.f};

#pragma unroll
  for (int wp = 0; wp < 8; ++wp) {
    const int p = 16 + wp;
    if (wp == 7) { PHASE_SYNC(0); }      // nothing left in flight
    else         { PHASE_SYNC(4); }
    if (wp < 6) stage(p + 2);            // stages Wo slots 18..23
    bf16x8 mf = mfrag[wp];
    const char* pb = wbuf + (p % 3) * 24576 + lane * 16;
#pragma unroll
    for (int jt = 0; jt < 16; ++jt) {
      bf16x8 wf = *(const bf16x8*)(pb + jt * 1024);
      acc[jt] = mfma16(wf, mf, acc[jt]);
    }
  }

  // epilogue: bias + NT stores; lane writes 16B chunks of its own full row
#pragma unroll
  for (int jt = 0; jt < 16; ++jt) {
    const int jj = jt * 16 + lg * 4;
    const float4 b4 = *(const float4*)(bo + jj);
    f32x4 o;
    o[0] = acc[jt][0] + b4.x;
    o[1] = acc[jt][1] + b4.y;
    o[2] = acc[jt][2] + b4.z;
    o[3] = acc[jt][3] + b4.w;
    __builtin_nontemporal_store(o, (f32x4*)(out + mrow * HID + jj));
  }
}

extern "C" void kernel_launch(void* const* d_in, const int* in_sizes, int n_in,
                              void* d_out, int out_size, void* d_ws, size_t ws_size,
                              hipStream_t stream) {
  (void)in_sizes; (void)n_in; (void)ws_size; (void)out_size;
  const float* fine   = (const float*)d_in[0];
  const float* coarse = (const float*)d_in[1];
  const float* motif  = (const float*)d_in[2];
  const float* Wq     = (const float*)d_in[3];
  const float* Wk     = (const float*)d_in[4];
  const float* Wv     = (const float*)d_in[5];
  const float* Wo     = (const float*)d_in[6];
  const float* bo     = (const float*)d_in[7];
  float* out          = (float*)d_out;
  bf16_t* wpk         = (bf16_t*)d_ws;

  pack_weights<<<128, 256, 0, stream>>>(Wq, Wk, Wv, Wo, wpk);
  fused_local_aug<<<B_TOT / BR, NTHR, 0, stream>>>(fine, coarse, motif, wpk, bo, out);
}